// Round 1
// 63.336 us; speedup vs baseline: 1.0274x; 1.0274x over previous
//
#include <hip/hip_runtime.h>
#include <math.h>

// PQC_26757646254573 — single-launch, scratch-free version.
//
// Analytical structure: out_b = exp(f1_b + i*f2_b) with
//   f_b = D[idx_last, idx_b] if idx_last < 8, else 0.
// setup_inputs() forces x[-1] = |x[-1]|+1 > 0 -> idx_last == 255 >= 8 ->
// c_shadow == 0 -> out == 1+0i everywhere. idx_last is still computed from x
// on device every call; the general path (idx_last < 8) is implemented as a
// per-block-redundant fp64 fallback so there is NO inter-block dependency
// (dispatch order / XCD coherence safe), it just never runs with live inputs.
//
// R1 changes vs 65 µs baseline:
//  1. SCRATCH ELIMINATION: the old heavy_path held double Mr[8][2][2]
//     indexed with runtime (rb,cb) -> local memory -> nonzero
//     private_segment_size on the *dispatch* even though the path is dead.
//     M = Rz@Rx has only 4 distinct scalars per qubit:
//       A=cx*cz, B=cx*sz, P=sx*sz, Q=sx*cz
//       M[0][0]=(A,B)  M[0][1]=(-P,Q)  M[1][0]=(P,Q)  M[1][1]=(A,-B)
//     selected with scalar ternaries (v_cndmask) from fully-unrolled
//     constant-indexed arrays -> registers only, scratch = 0.
//  2. STORE-FIRST: the constant (1,0) output is written before the x-load /
//     `general` check, so the live-path stores no longer wait on a dependent
//     (possibly cold) global load.
//  3. 32 blocks (one float4 per thread) + noinline heavy path: hot code is
//     ~20 instructions; dead fp64 body stays out of the fast fetch path.

#define NQ 8
#define NL 6
#define QDIM 256
#define BATCH 16384

// per-block workspace slice layout (doubles):
//   U: 131072, T: 131072, R: 131072, v: 2*256
#define OFF_U 0
#define OFF_T 131072
#define OFF_R 262144
#define OFF_V 393216
#define SLICE_DOUBLES 393728  // 393216 + 512

__device__ __forceinline__ int compute_idx(const float* __restrict__ xrow) {
  int v = 0;
#pragma unroll
  for (int j = 0; j < NQ; ++j)
    v |= (xrow[j] > 0.0f) ? (1 << (NQ - 1 - j)) : 0;
  return v;
}

// Full fp64 fallback, executed per-block (redundantly) only when idxl < 8.
// Thread t owns row t of U. Writes v[2][256] into this block's slice.
// No per-thread arrays with runtime indices -> zero scratch.
__device__ __attribute__((noinline)) void heavy_path(
    int t, int idxl,
    const float* __restrict__ qx1, const float* __restrict__ qz1,
    const float* __restrict__ qx2, const float* __restrict__ qz2,
    double* __restrict__ W)
{
  double* U = W + OFF_U;
  double* T = W + OFF_T;
  double* R = W + OFF_R;
  const double ainv = 0.8705505632961241;  // 2^-0.2

  for (int circ = 0; circ < 2; ++circ) {
    const float* qx = circ ? qx2 : qx1;
    const float* qz = circ ? qz2 : qz1;

    for (int c = 0; c < QDIM; ++c) {
      U[((size_t)t * QDIM + c) * 2 + 0] = (c == t) ? 1.0 : 0.0;
      U[((size_t)t * QDIM + c) * 2 + 1] = 0.0;
    }

    for (int l = 0; l < NL; ++l) {
      // Per-qubit single-qubit gate M = Rz(qz)@Rx(qx); only 4 distinct
      // scalars per qubit. Constant-indexed (fully unrolled) arrays stay
      // in registers.
      double A[NQ], B[NQ], P[NQ], Q[NQ];
#pragma unroll
      for (int j = 0; j < NQ; ++j) {
        double hx = 0.5 * (double)qx[l * NQ + j];
        double hz = 0.5 * (double)qz[l * NQ + j];
        double cx = cos(hx), sx = sin(hx), cz = cos(hz), sz = sin(hz);
        A[j] = cx * cz;  // M[0][0].re =  A ; M[1][1].re =  A
        B[j] = cx * sz;  // M[0][0].im =  B ; M[1][1].im = -B
        P[j] = sx * sz;  // M[1][0].re =  P ; M[0][1].re = -P
        Q[j] = sx * cz;  // M[1][0].im =  Q ; M[0][1].im =  Q
      }

      __syncthreads();  // done reading previous R
      for (int c = 0; c < QDIM; ++c) {
        double ar = 1.0, ai = 0.0;
#pragma unroll
        for (int j = 0; j < NQ; ++j) {
          int rb = (t >> (NQ - 1 - j)) & 1;
          int cb = (c >> (NQ - 1 - j)) & 1;
          // M[rb][cb] via scalar selects (v_cndmask), no memory:
          double br, bi;
          if (rb == cb) { br = A[j]; bi = rb ? -B[j] : B[j]; }
          else          { br = rb ? P[j] : -P[j]; bi = Q[j]; }
          double nr = ar * br - ai * bi;
          ai = ar * bi + ai * br;
          ar = nr;
        }
        R[((size_t)t * QDIM + c) * 2 + 0] = ar;
        R[((size_t)t * QDIM + c) * 2 + 1] = ai;
      }
      __syncthreads();  // R built

      for (int n = 0; n < NQ - 1; ++n) {
        // U = U @ C_n (column op, row-local)
        const int bn = NQ - 1 - n;
        const int fm = 1 << (NQ - 2 - n);
        for (int c = 0; c < QDIM; ++c) {
          size_t pc = ((size_t)t * QDIM + c) * 2;
          if (((c >> bn) & 1) == 0) {
            U[pc + 0] *= ainv;
            U[pc + 1] *= ainv;
          } else if ((c & fm) == 0) {
            int c2 = c | fm;
            size_t p2 = ((size_t)t * QDIM + c2) * 2;
            double ar = U[pc + 0], ai = U[pc + 1];
            double br = U[p2 + 0], bi = U[p2 + 1];
            U[pc + 0] = (ar - 2.0 * ai + 2.0 * bi) * ainv;
            U[pc + 1] = (ai + 2.0 * ar - 2.0 * br) * ainv;
            U[p2 + 0] = (br - 2.0 * bi + 2.0 * ai) * ainv;
            U[p2 + 1] = (bi + 2.0 * br - 2.0 * ar) * ainv;
          }
        }
        // U = U @ R (dense row t)
        for (int c = 0; c < QDIM; ++c) {
          double ar = 0.0, ai = 0.0;
          for (int k = 0; k < QDIM; ++k) {
            double ur = U[((size_t)t * QDIM + k) * 2 + 0];
            double ui = U[((size_t)t * QDIM + k) * 2 + 1];
            double rr = R[((size_t)k * QDIM + c) * 2 + 0];
            double ri = R[((size_t)k * QDIM + c) * 2 + 1];
            ar += ur * rr - ui * ri;
            ai += ur * ri + ui * rr;
          }
          T[((size_t)t * QDIM + c) * 2 + 0] = ar;
          T[((size_t)t * QDIM + c) * 2 + 1] = ai;
        }
        for (int c = 0; c < QDIM; ++c) {
          U[((size_t)t * QDIM + c) * 2 + 0] = T[((size_t)t * QDIM + c) * 2 + 0];
          U[((size_t)t * QDIM + c) * 2 + 1] = T[((size_t)t * QDIM + c) * 2 + 1];
        }
      }
    }

    // U @ H, H[k][c] = (1/16)*(-1)^popc(k&c)
    for (int c = 0; c < QDIM; ++c) {
      double ar = 0.0, ai = 0.0;
      for (int k = 0; k < QDIM; ++k) {
        double s = (__popc(k & c) & 1) ? -1.0 : 1.0;
        ar += U[((size_t)t * QDIM + k) * 2 + 0] * s;
        ai += U[((size_t)t * QDIM + k) * 2 + 1] * s;
      }
      T[((size_t)t * QDIM + c) * 2 + 0] = ar * 0.0625;
      T[((size_t)t * QDIM + c) * 2 + 1] = ai * 0.0625;
    }
    __syncthreads();  // T built

    {
      double acc = 0.0;
      for (int m = 0; m < QDIM; ++m) {
        double s = ((m >> (NQ - 1 - idxl)) & 1) ? -1.0 : 1.0;
        double re = T[((size_t)m * QDIM + t) * 2 + 0];
        double im = T[((size_t)m * QDIM + t) * 2 + 1];
        acc += s * (re * re + im * im);
      }
      W[OFF_V + circ * QDIM + t] = acc;
    }
    __syncthreads();  // done reading T before next circuit
  }
  __syncthreads();  // v visible to whole block before output phase
}

// One launch: nblocks × 256. Each thread writes `per_thread` complex values.
__global__ __launch_bounds__(256) void fused_kernel(
    const float* __restrict__ x,
    const float* __restrict__ qx1, const float* __restrict__ qz1,
    const float* __restrict__ qx2, const float* __restrict__ qz2,
    double* __restrict__ Wbase,
    float* __restrict__ out, int n_complex, int interleaved, int per_thread)
{
  const int t = threadIdx.x;
  const int base = (blockIdx.x * blockDim.x + t) * per_thread;

  // ---- Phase 1: unconditional constant store (the live result). ----
  // Issued before any dependent load so the common path retires ASAP.
  if (interleaved && per_thread == 2 && base + 2 <= n_complex &&
      (((uintptr_t)out) & 15) == 0) {
    // 2 complex = one float4 store of (1,0,1,0)
    float4 v; v.x = 1.0f; v.y = 0.0f; v.z = 1.0f; v.w = 0.0f;
    reinterpret_cast<float4*>(out)[base >> 1] = v;
  } else {
    for (int r = 0; r < per_thread; ++r) {
      int b = base + r;
      if (b >= n_complex) break;
      if (interleaved) {
        float2 v; v.x = 1.0f; v.y = 0.0f;
        reinterpret_cast<float2*>(out)[b] = v;
      } else {
        out[b] = 1.0f;
      }
    }
  }

  // ---- Phase 2: trigger check (uniform); dead with live inputs. ----
  const int idxl = compute_idx(x + (size_t)(BATCH - 1) * NQ);
  if (idxl >= NQ) return;

  // ---- General fp64 fallback: recompute and overwrite. ----
  double* W = Wbase + (size_t)blockIdx.x * SLICE_DOUBLES;
  heavy_path(t, idxl, qx1, qz1, qx2, qz2, W);

  for (int r = 0; r < per_thread; ++r) {
    int b = base + r;
    if (b >= n_complex) break;
    const int ib = compute_idx(x + (size_t)b * NQ);
    double f1 = W[OFF_V + 0 * QDIM + ib];
    double f2 = W[OFF_V + 1 * QDIM + ib];
    double e = exp(f1);
    float re = (float)(e * cos(f2));
    float im = (float)(e * sin(f2));
    if (interleaved) {
      float2 v; v.x = re; v.y = im;
      reinterpret_cast<float2*>(out)[b] = v;
    } else {
      out[b] = re;
    }
  }
}

extern "C" void kernel_launch(void* const* d_in, const int* in_sizes, int n_in,
                              void* d_out, int out_size, void* d_ws, size_t ws_size,
                              hipStream_t stream) {
  const float* x   = (const float*)d_in[0];
  const float* qx1 = (const float*)d_in[1];
  const float* qz1 = (const float*)d_in[2];
  const float* qx2 = (const float*)d_in[3];
  const float* qz2 = (const float*)d_in[4];
  // d_in[5]/d_in[6] (c1,c2) are dead in the reference (_f ignores c_embed)

  double* W  = (double*)d_ws;
  float* out = (float*)d_out;

  const int interleaved = (out_size == 2 * BATCH) ? 1 : 0;
  const int n = interleaved ? (out_size / 2) : out_size;

  // Each block needs its own fallback slice; cap block count by ws capacity.
  const size_t slice_bytes = (size_t)SLICE_DOUBLES * sizeof(double);
  int max_blocks = (int)(ws_size / slice_bytes);
  if (max_blocks < 1) max_blocks = 1;  // ws_size is known >= one slice (3.2 MB)
  int nblocks = 32 < max_blocks ? 32 : max_blocks;
  int per_thread = (n + nblocks * 256 - 1) / (nblocks * 256);

  fused_kernel<<<nblocks, 256, 0, stream>>>(x, qx1, qz1, qx2, qz2, W, out,
                                            n, interleaved, per_thread);
}